// Round 8
// baseline (716.047 us; speedup 1.0000x reference)
//
#include <hip/hip_runtime.h>
#include <hip/hip_bf16.h>
#include <math.h>

typedef unsigned short ushortT;
typedef __attribute__((ext_vector_type(8))) short short8;
typedef __attribute__((ext_vector_type(4))) short short4v;
typedef __attribute__((ext_vector_type(4))) float f32x4;
typedef __attribute__((ext_vector_type(4))) float float4v;

#define TOK 65536
#define NSEQ 4096
#define DIM 512

__device__ __forceinline__ float bf2f(ushortT u) {
  union { float f; unsigned int i; } v; v.i = ((unsigned int)u) << 16; return v.f;
}
__device__ __forceinline__ ushortT f2bf(float f) {
  union { float f; unsigned int i; } v; v.f = f;
  unsigned int r = v.i + 0x7fffu + ((v.i >> 16) & 1u);
  return (ushortT)(r >> 16);
}

// exact-grade GELU via A&S 7.1.26 erf (|err| ~1e-6)
__device__ __forceinline__ float fast_gelu(float x) {
  const float y = fabsf(x) * 0.70710678118654752f;
  const float t = __builtin_amdgcn_rcpf(__builtin_fmaf(0.3275911f, y, 1.f));
  float p = 1.061405429f;
  p = __builtin_fmaf(p, t, -1.453152027f);
  p = __builtin_fmaf(p, t, 1.421413741f);
  p = __builtin_fmaf(p, t, -0.284496736f);
  p = __builtin_fmaf(p, t, 0.254829592f);
  p = p * t;
  const float e = __builtin_amdgcn_exp2f(-y * y * 1.4426950408889634f);
  float erfv = __builtin_fmaf(-p, e, 1.f);
  erfv = copysignf(erfv, x);
  return 0.5f * x * (1.f + erfv);
}

#define GLOAD_LDS(gp, lp) __builtin_amdgcn_global_load_lds( \
    (const __attribute__((address_space(1))) unsigned int*)(gp), \
    (__attribute__((address_space(3))) unsigned int*)(lp), 16, 0, 0)

#define BAR __builtin_amdgcn_s_barrier()
#define VMC(n) asm volatile("s_waitcnt vmcnt(" #n ")" ::: "memory")
#define SB0 __builtin_amdgcn_sched_barrier(0)

// ---------------- weight f32 -> bf16 convert ----------------
__global__ void cvt_kernel(const float* __restrict__ in, ushortT* __restrict__ out, int n4) {
  int i = blockIdx.x * 256 + threadIdx.x;
  if (i >= n4) return;
  float4v v = *(const float4v*)(in + (size_t)i * 4);
  short4v o;
#pragma unroll
  for (int j = 0; j < 4; ++j) o[j] = (short)f2bf(v[j]);
  *(short4v*)(out + (size_t)i * 4) = o;
}

// ---------------- LayerNorm (one wave per token) ----------------
template <bool INBF>
__global__ __launch_bounds__(256)
void ln_kernel(const void* __restrict__ inp, const float* __restrict__ gw,
               const float* __restrict__ bw, ushortT* __restrict__ out)
{
  const int lane = threadIdx.x & 63;
  const size_t tok = (size_t)blockIdx.x * 4 + (threadIdx.x >> 6);
  const int col = lane * 8;
  float x[8];
  if constexpr (INBF) {
    short8 v = *(const short8*)((const ushortT*)inp + tok * DIM + col);
#pragma unroll
    for (int j = 0; j < 8; ++j) x[j] = bf2f((ushortT)v[j]);
  } else {
    const float* p = (const float*)inp + tok * DIM + col;
    float4v a = *(const float4v*)p, b = *(const float4v*)(p + 4);
#pragma unroll
    for (int j = 0; j < 4; ++j) { x[j] = a[j]; x[4 + j] = b[j]; }
  }
  float s = 0.f, ss = 0.f;
#pragma unroll
  for (int j = 0; j < 8; ++j) { s += x[j]; ss += x[j] * x[j]; }
#pragma unroll
  for (int off = 1; off < 64; off <<= 1) {
    s += __shfl_xor(s, off, 64);
    ss += __shfl_xor(ss, off, 64);
  }
  const float mean = s * (1.f / 512.f);
  const float var = ss * (1.f / 512.f) - mean * mean;
  const float rstd = rsqrtf(var + 1e-5f);
  float4v g1 = *(const float4v*)(gw + col), g2 = *(const float4v*)(gw + col + 4);
  float4v b1 = *(const float4v*)(bw + col), b2 = *(const float4v*)(bw + col + 4);
  short8 o;
#pragma unroll
  for (int j = 0; j < 4; ++j) {
    o[j]     = (short)f2bf((x[j]     - mean) * rstd * g1[j] + b1[j]);
    o[4 + j] = (short)f2bf((x[4 + j] - mean) * rstd * g2[j] + b2[j]);
  }
  *(short8*)(out + tok * DIM + col) = o;
}

// ---------------- 256x256 GEMM, BK=32, 4-buffer deep pipeline ----------------
// T4 counted-vmcnt: stage tile t+3 during body t; boundary waits vmcnt(8)
// (keeps newest 2 staged tiles in flight, drains tile t+1 -> ready).
// LDS layout per buffer: A[256 rows][4 chunks of 8 bf16], slot = c ^ (r&3) ^ ((r>>2)&3);
// source address carries the inverse swizzle (lane-only: (l&3)^((l>>2)&3)^(l>>4)),
// LDS dest stays linear as global_load_lds requires.
#define STG(bA, bB, kt) do { \
    const ushortT* _ga = gA + (size_t)(kt) * 32; \
    const ushortT* _gb = gB + (size_t)(kt) * 32; \
    GLOAD_LDS(_ga,                  (bA) + w * 1024); \
    GLOAD_LDS(_ga + (size_t)16 * K, (bA) + w * 1024 + 512); \
    GLOAD_LDS(_gb,                  (bB) + w * 1024); \
    GLOAD_LDS(_gb + (size_t)16 * K, (bB) + w * 1024 + 512); \
  } while (0)

template <int EPI>
__global__ __launch_bounds__(512, 2)
void gemm256(const ushortT* __restrict__ A, const ushortT* __restrict__ Bt,
             const float* __restrict__ bias, int M, int N, int K,
             ushortT* __restrict__ outb, float* __restrict__ outf,
             const float* __restrict__ resf, const ushortT* __restrict__ resb)
{
  __shared__ __align__(16) ushortT sm[65536];   // 128 KiB = 4 buf x (A 16KB + B 16KB)

  const int tid = threadIdx.x;
  const int w = tid >> 6, l = tid & 63;
  const int wr = w >> 2, wc = w & 3;

  // XCD-bijective swizzle
  const int nwg = gridDim.x * gridDim.y;
  int wg = blockIdx.y * gridDim.x + blockIdx.x;
  {
    const int q = nwg >> 3, r8 = nwg & 7;
    const int xc = wg & 7, yc = wg >> 3;
    wg = (xc < r8 ? xc * (q + 1) : r8 * (q + 1) + (xc - r8) * q) + yc;
  }
  const int nbn = N >> 8;
  const int mb = wg / nbn, nb = wg % nbn;
  const int m0 = mb << 8, n0 = nb << 8;
  const int NT = K >> 5;   // BK = 32, NT >= 16

  // staging source (per-lane inverse swizzle; 4 lanes cover one full 64B row)
  const int scw = ((l & 3) ^ ((l >> 2) & 3) ^ (l >> 4)) << 3;
  const ushortT* gA = A  + (size_t)(m0 + w * 32 + (l >> 2)) * K + scw;
  const ushortT* gB = Bt + (size_t)(n0 + w * 32 + (l >> 2)) * K + scw;

  // ds_read addressing: frag(m): row = wr*128 + m*16 + rl, chunk = ql
  const int rl = l & 15, ql = l >> 4;
  const int xr = (rl & 3) ^ ((rl >> 2) & 3);
  const int aoff = (wr * 128 + rl) * 32 + ((ql ^ xr) << 3);
  const int boff = (wc * 64 + rl) * 32 + ((ql ^ xr) << 3);

  f32x4 acc[8][4];
  const f32x4 zero = {0.f, 0.f, 0.f, 0.f};
#pragma unroll
  for (int i = 0; i < 8; ++i)
#pragma unroll
    for (int j = 0; j < 4; ++j) acc[i][j] = zero;

  ushortT* a0 = sm;              ushortT* b0 = sm + 8192;
  ushortT* a1 = sm + 16384;      ushortT* b1 = sm + 24576;
  ushortT* a2 = sm + 32768;      ushortT* b2 = sm + 40960;
  ushortT* a3 = sm + 49152;      ushortT* b3 = sm + 57344;

  // prologue: stage tiles 0,1,2 (NT >= 16); wait tile 0 (keep 8 = tiles 1,2 in flight)
  STG(a0, b0, 0);
  STG(a1, b1, 1);
  STG(a2, b2, 2);
  VMC(8);
  BAR; SB0;

  short8 Af[8], Bf[4];

  for (int t = 0; t < NT; ++t) {
    if (t + 3 < NT) STG(a3, b3, t + 3);
#pragma unroll
    for (int m = 0; m < 8; ++m) Af[m] = *(const short8*)(a0 + aoff + m * 512);
#pragma unroll
    for (int n = 0; n < 4; ++n) Bf[n] = *(const short8*)(b0 + boff + n * 512);
#pragma unroll
    for (int m = 0; m < 8; ++m)
#pragma unroll
      for (int n = 0; n < 4; ++n)
        acc[m][n] = __builtin_amdgcn_mfma_f32_16x16x32_bf16(Af[m], Bf[n], acc[m][n], 0, 0, 0);
    // ---- boundary: drain tile t+1 only (counted, never 0 mid-loop) ----
    SB0;
    if (t + 4 <= NT)      { VMC(8); }   // tiles t+2,t+3 stay in flight
    else if (t + 3 == NT) { VMC(4); }   // tile t+2 stays in flight
    else if (t + 2 == NT) { VMC(0); }   // final drain
    BAR; SB0;
    ushortT* tp;
    tp = a0; a0 = a1; a1 = a2; a2 = a3; a3 = tp;
    tp = b0; b0 = b1; b1 = b2; b2 = b3; b3 = tp;
  }

  // ---- epilogue: LDS round-trip -> fully coalesced stores ----
  float* const ep = (float*)sm;   // 32768 f32 = 128 KiB
#pragma unroll
  for (int p = 0; p < 2; ++p) {
    if (p) BAR;                   // protect overwrite from pass-0 readers
    if (wr == p) {
#pragma unroll
      for (int m = 0; m < 8; ++m) {
#pragma unroll
        for (int n = 0; n < 4; ++n) {
          const int c = wc * 64 + n * 16 + rl;
          const int pc = c ^ (c >> 3);
          *(f32x4*)(ep + (m * 4 + ql) * 1024 + pc * 4) = acc[m][n];
        }
      }
    }
    BAR;
#pragma unroll
    for (int k = 0; k < 4; ++k) {
      const int rb = w + k * 8;
      const int rowb = 16 * (rb >> 2) + 4 * (rb & 3);
      f32x4 rv[4];
#pragma unroll
      for (int j = 0; j < 4; ++j) {
        const int c = 4 * l + j;
        const int pc = c ^ (c >> 3);
        rv[j] = *(const f32x4*)(ep + rb * 1024 + pc * 4);
      }
      const int col = n0 + 4 * l;
      const float4v bb = *(const float4v*)(bias + col);
#pragma unroll
      for (int i = 0; i < 4; ++i) {
        const size_t row = (size_t)(m0 + p * 128 + rowb + i);
        float v0 = rv[0][i] + bb[0], v1 = rv[1][i] + bb[1],
              v2 = rv[2][i] + bb[2], v3 = rv[3][i] + bb[3];
        if constexpr (EPI == 1) {
          const float4v rr = *(const float4v*)(resf + row * (size_t)N + col);
          v0 += rr[0]; v1 += rr[1]; v2 += rr[2]; v3 += rr[3];
        }
        if constexpr (EPI == 2) {
          v0 = fast_gelu(v0); v1 = fast_gelu(v1); v2 = fast_gelu(v2); v3 = fast_gelu(v3);
        }
        if constexpr (EPI == 3) {
          const short4v rb4 = *(const short4v*)(resb + row * (size_t)N + col);
          v0 += bf2f((ushortT)rb4[0]); v1 += bf2f((ushortT)rb4[1]);
          v2 += bf2f((ushortT)rb4[2]); v3 += bf2f((ushortT)rb4[3]);
          float4v o = {v0, v1, v2, v3};
          *(float4v*)(outf + row * (size_t)N + col) = o;
        } else {
          short4v o;
          o[0] = (short)f2bf(v0); o[1] = (short)f2bf(v1);
          o[2] = (short)f2bf(v2); o[3] = (short)f2bf(v3);
          *(short4v*)(outb + row * (size_t)N + col) = o;
        }
      }
    }
  }
}

// ---------------- windowed attention (one block/window, one wave/head) ----------------
__global__ __launch_bounds__(512)
void attn_kernel(const ushortT* __restrict__ qkv, ushortT* __restrict__ out)
{
  __shared__ __align__(16) ushortT sq[8][1544];
  const int wb = blockIdx.x;
  const int b  = wb >> 9;
  const int rr = wb & 511;
  const int w1 = rr >> 6;
  const int g  = rr & 63;
  const int tid = threadIdx.x;

#pragma unroll
  for (int c = 0; c < 3; ++c) {
    const int f = c * 512 + tid;
    const int i = f / 192;
    const int col = (f % 192) * 8;
    const int tin = (64 * g + 8 * i + w1 + 4) & (NSEQ - 1);
    const ushortT* src = qkv + ((size_t)b * NSEQ + tin) * 1536 + col;
    *(short8*)(&sq[i][col]) = *(const short8*)src;
  }
  __syncthreads();

  const int wave = tid >> 6, lane = tid & 63;
  const int h = wave;
  const int qi = lane >> 3, kj = lane & 7;

  float s = 0.f;
  const ushortT* qrow = &sq[qi][h * 64];
  const ushortT* krow = &sq[kj][512 + h * 64];
#pragma unroll
  for (int c = 0; c < 8; ++c) {
    short8 qa = *(const short8*)(qrow + c * 8);
    short8 ka = *(const short8*)(krow + c * 8);
#pragma unroll
    for (int j = 0; j < 8; ++j) s += bf2f((ushortT)qa[j]) * bf2f((ushortT)ka[j]);
  }
  s *= 0.125f;

  const int pq = 64 * g + 8 * qi + w1;
  const int pk = 64 * g + 8 * kj + w1;
  const int cq = (pq < 4088) ? 0 : (pq < 4092 ? 1 : 2);
  const int ck = (pk < 4088) ? 0 : (pk < 4092 ? 1 : 2);
  if (cq != ck) s -= 100.f;

  float mx = s;
  mx = fmaxf(mx, __shfl_xor(mx, 1, 64));
  mx = fmaxf(mx, __shfl_xor(mx, 2, 64));
  mx = fmaxf(mx, __shfl_xor(mx, 4, 64));
  const float e = expf(s - mx);
  float sum = e;
  sum += __shfl_xor(sum, 1, 64);
  sum += __shfl_xor(sum, 2, 64);
  sum += __shfl_xor(sum, 4, 64);
  const float p = e / sum;

  const int dc = lane & 7;
  float o[8];
#pragma unroll
  for (int j = 0; j < 8; ++j) o[j] = 0.f;
#pragma unroll
  for (int k2 = 0; k2 < 8; ++k2) {
    const float pk2 = __shfl(p, (lane & ~7) + k2, 64);
    short8 va = *(const short8*)(&sq[k2][1024 + h * 64 + dc * 8]);
#pragma unroll
    for (int j = 0; j < 8; ++j) o[j] += pk2 * bf2f((ushortT)va[j]);
  }

  const int tout = (512 * qi + 64 * w1 + g + 4) & (NSEQ - 1);
  short8 ov;
#pragma unroll
  for (int j = 0; j < 8; ++j) ov[j] = (short)f2bf(o[j]);
  *(short8*)(out + ((size_t)b * NSEQ + tout) * DIM + h * 64 + dc * 8) = ov;
}

// ---------------- host ----------------
extern "C" void kernel_launch(void* const* d_in, const int* in_sizes, int n_in,
                              void* d_out, int out_size, void* d_ws, size_t ws_size,
                              hipStream_t stream) {
  const float* x      = (const float*)d_in[0];
  const float* n1g    = (const float*)d_in[1];
  const float* n1b    = (const float*)d_in[2];
  const float* qkv_w  = (const float*)d_in[3];
  const float* qkv_b  = (const float*)d_in[4];
  const float* proj_w = (const float*)d_in[5];
  const float* proj_b = (const float*)d_in[6];
  const float* n2g    = (const float*)d_in[7];
  const float* n2b    = (const float*)d_in[8];
  const float* fc1_w  = (const float*)d_in[9];
  const float* fc1_b  = (const float*)d_in[10];
  const float* fc2_w  = (const float*)d_in[11];
  const float* fc2_b  = (const float*)d_in[12];
  float* out = (float*)d_out;

  size_t off = 0;
  char* ws = (char*)d_ws;
  auto alloc = [&](size_t b) { void* p = ws + off; off += (b + 255) & ~(size_t)255; return p; };

  ushortT* qkvw_b = (ushortT*)alloc((size_t)1536 * 512 * 2);
  ushortT* projw_b = (ushortT*)alloc((size_t)512 * 512 * 2);
  ushortT* fc1w_b = (ushortT*)alloc((size_t)2048 * 512 * 2);
  ushortT* fc2w_b = (ushortT*)alloc((size_t)512 * 2048 * 2);
  ushortT* bufA = (ushortT*)alloc((size_t)TOK * 512 * 2);    // xn -> attnout -> h_in
  ushortT* bufQ = (ushortT*)alloc((size_t)TOK * 1536 * 2);   // qkv ; then x1 (bf16)
  ushortT* x1 = bufQ;

  int nch = 1;
  while (nch < 16) {
    size_t need = (size_t)(TOK / nch) * 2048 * 2;
    if (off + need <= ws_size) break;
    nch <<= 1;
  }
  ushortT* h1 = (ushortT*)(ws + off);

  cvt_kernel<<<(1536 * 512 / 4 + 255) / 256, 256, 0, stream>>>(qkv_w, qkvw_b, 1536 * 512 / 4);
  cvt_kernel<<<(512 * 512 / 4 + 255) / 256, 256, 0, stream>>>(proj_w, projw_b, 512 * 512 / 4);
  cvt_kernel<<<(2048 * 512 / 4 + 255) / 256, 256, 0, stream>>>(fc1_w, fc1w_b, 2048 * 512 / 4);
  cvt_kernel<<<(512 * 2048 / 4 + 255) / 256, 256, 0, stream>>>(fc2_w, fc2w_b, 512 * 2048 / 4);

  ln_kernel<false><<<TOK / 4, 256, 0, stream>>>(x, n1g, n1b, bufA);

  gemm256<0><<<dim3(TOK / 256, 1536 / 256), 512, 0, stream>>>(
      bufA, qkvw_b, qkv_b, TOK, 1536, 512, bufQ, nullptr, nullptr, nullptr);

  attn_kernel<<<8192, 512, 0, stream>>>(bufQ, bufA);

  gemm256<1><<<dim3(TOK / 256, 512 / 256), 512, 0, stream>>>(
      bufA, projw_b, proj_b, TOK, 512, 512, x1, nullptr, x, nullptr);

  ln_kernel<true><<<TOK / 4, 256, 0, stream>>>(x1, n2g, n2b, bufA);

  const int tc = TOK / nch;
  for (int c = 0; c < nch; ++c) {
    const ushortT* hin = bufA + (size_t)c * tc * 512;
    gemm256<2><<<dim3(tc / 256, 2048 / 256), 512, 0, stream>>>(
        hin, fc1w_b, fc1_b, tc, 2048, 512, h1, nullptr, nullptr, nullptr);
    gemm256<3><<<dim3(tc / 256, 512 / 256), 512, 0, stream>>>(
        h1, fc2w_b, fc2_b, tc, 512, 2048, nullptr, out + (size_t)c * tc * 512,
        nullptr, x1 + (size_t)c * tc * 512);
  }
}

// Round 9
// 682.129 us; speedup vs baseline: 1.0497x; 1.0497x over previous
//
#include <hip/hip_runtime.h>
#include <hip/hip_bf16.h>
#include <math.h>

typedef unsigned short ushortT;
typedef __attribute__((ext_vector_type(8))) short short8;
typedef __attribute__((ext_vector_type(4))) short short4v;
typedef __attribute__((ext_vector_type(4))) float f32x4;
typedef __attribute__((ext_vector_type(4))) float float4v;

#define TOK 65536
#define NSEQ 4096
#define DIM 512

__device__ __forceinline__ float bf2f(ushortT u) {
  union { float f; unsigned int i; } v; v.i = ((unsigned int)u) << 16; return v.f;
}
__device__ __forceinline__ ushortT f2bf(float f) {
  union { float f; unsigned int i; } v; v.f = f;
  unsigned int r = v.i + 0x7fffu + ((v.i >> 16) & 1u);
  return (ushortT)(r >> 16);
}

// exact-grade GELU via A&S 7.1.26 erf (|err| ~1e-6)
__device__ __forceinline__ float fast_gelu(float x) {
  const float y = fabsf(x) * 0.70710678118654752f;
  const float t = __builtin_amdgcn_rcpf(__builtin_fmaf(0.3275911f, y, 1.f));
  float p = 1.061405429f;
  p = __builtin_fmaf(p, t, -1.453152027f);
  p = __builtin_fmaf(p, t, 1.421413741f);
  p = __builtin_fmaf(p, t, -0.284496736f);
  p = __builtin_fmaf(p, t, 0.254829592f);
  p = p * t;
  const float e = __builtin_amdgcn_exp2f(-y * y * 1.4426950408889634f);
  float erfv = __builtin_fmaf(-p, e, 1.f);
  erfv = copysignf(erfv, x);
  return 0.5f * x * (1.f + erfv);
}

#define GLOAD_LDS(gp, lp) __builtin_amdgcn_global_load_lds( \
    (const __attribute__((address_space(1))) unsigned int*)(gp), \
    (__attribute__((address_space(3))) unsigned int*)(lp), 16, 0, 0)

#define BAR __builtin_amdgcn_s_barrier()
#define VMC(n) asm volatile("s_waitcnt vmcnt(" #n ")" ::: "memory")
#define SB0 __builtin_amdgcn_sched_barrier(0)
#define STR2(x) #x
// inline-asm ds_read: invisible to the compiler's waitcnt tracking, so our
// counted lgkmcnt is the ONLY wait. SB0 after each wait (rule #18).
#define DSR(dst, addr, IMM) \
  asm volatile("ds_read_b128 %0, %1 offset:" STR2(IMM) : "=v"(dst) : "v"(addr))
#define LGKM(n) do { asm volatile("s_waitcnt lgkmcnt(" #n ")" ::: "memory"); \
                     __builtin_amdgcn_sched_barrier(0); } while (0)

// ---------------- weight f32 -> bf16 convert ----------------
__global__ void cvt_kernel(const float* __restrict__ in, ushortT* __restrict__ out, int n4) {
  int i = blockIdx.x * 256 + threadIdx.x;
  if (i >= n4) return;
  float4v v = *(const float4v*)(in + (size_t)i * 4);
  short4v o;
#pragma unroll
  for (int j = 0; j < 4; ++j) o[j] = (short)f2bf(v[j]);
  *(short4v*)(out + (size_t)i * 4) = o;
}

// ---------------- LayerNorm (one wave per token) ----------------
template <bool INBF>
__global__ __launch_bounds__(256)
void ln_kernel(const void* __restrict__ inp, const float* __restrict__ gw,
               const float* __restrict__ bw, ushortT* __restrict__ out)
{
  const int lane = threadIdx.x & 63;
  const size_t tok = (size_t)blockIdx.x * 4 + (threadIdx.x >> 6);
  const int col = lane * 8;
  float x[8];
  if constexpr (INBF) {
    short8 v = *(const short8*)((const ushortT*)inp + tok * DIM + col);
#pragma unroll
    for (int j = 0; j < 8; ++j) x[j] = bf2f((ushortT)v[j]);
  } else {
    const float* p = (const float*)inp + tok * DIM + col;
    float4v a = *(const float4v*)p, b = *(const float4v*)(p + 4);
#pragma unroll
    for (int j = 0; j < 4; ++j) { x[j] = a[j]; x[4 + j] = b[j]; }
  }
  float s = 0.f, ss = 0.f;
#pragma unroll
  for (int j = 0; j < 8; ++j) { s += x[j]; ss += x[j] * x[j]; }
#pragma unroll
  for (int off = 1; off < 64; off <<= 1) {
    s += __shfl_xor(s, off, 64);
    ss += __shfl_xor(ss, off, 64);
  }
  const float mean = s * (1.f / 512.f);
  const float var = ss * (1.f / 512.f) - mean * mean;
  const float rstd = rsqrtf(var + 1e-5f);
  float4v g1 = *(const float4v*)(gw + col), g2 = *(const float4v*)(gw + col + 4);
  float4v b1 = *(const float4v*)(bw + col), b2 = *(const float4v*)(bw + col + 4);
  short8 o;
#pragma unroll
  for (int j = 0; j < 4; ++j) {
    o[j]     = (short)f2bf((x[j]     - mean) * rstd * g1[j] + b1[j]);
    o[4 + j] = (short)f2bf((x[4 + j] - mean) * rstd * g2[j] + b2[j]);
  }
  *(short8*)(out + tok * DIM + col) = o;
}

// ---------------- 256x256 GEMM, register-double-buffered K-tile ----------------
// LDS bytes: A0@0, A1@32768, B0@65536, B1@98304 (flip = XOR 0x8000).
// Per tile: 12 ks0-reads in flight at entry; counted lgkm waits release each
// 16-MFMA quadrant while the next quadrant's reads fly. Boundary: VMC(0)+BAR.
#define STAGE_A2(bufp, h, gptr) do { \
    GLOAD_LDS((gptr) + (size_t)((h) * 128) * K,     (bufp) + (h) * 8192 + w * 1024); \
    GLOAD_LDS((gptr) + (size_t)((h) * 128 + 8) * K, (bufp) + (h) * 8192 + w * 1024 + 512); \
  } while (0)
#define STAGE_B2(bufp, h, gptr) do { \
    GLOAD_LDS((gptr) + (size_t)((h) * 128) * K,     (bufp) + (h) * 8192 + w * 1024); \
    GLOAD_LDS((gptr) + (size_t)((h) * 128 + 8) * K, (bufp) + (h) * 8192 + w * 1024 + 512); \
  } while (0)

#define DSR_KS0() do { \
    DSR(AfX[0], adrA, 0);    DSR(AfX[1], adrA, 2048); \
    DSR(AfX[2], adrA, 4096); DSR(AfX[3], adrA, 6144); \
    DSR(BfC[0], adrB, 0);    DSR(BfC[1], adrB, 2048); \
    DSR(BfC[2], adrB, 4096); DSR(BfC[3], adrB, 6144); \
    DSR(AfY[0], adrA, 8192);  DSR(AfY[1], adrA, 10240); \
    DSR(AfY[2], adrA, 12288); DSR(AfY[3], adrA, 14336); \
  } while (0)

#define QUAD(AF, BF, MB) \
  _Pragma("unroll") \
  for (int m_ = 0; m_ < 4; ++m_) \
    _Pragma("unroll") \
    for (int n_ = 0; n_ < 4; ++n_) \
      acc[(MB) + m_][n_] = __builtin_amdgcn_mfma_f32_16x16x32_bf16( \
          AF[m_], BF[n_], acc[(MB) + m_][n_], 0, 0, 0)

template <int EPI>
__global__ __launch_bounds__(512, 2)
void gemm256(const ushortT* __restrict__ A, const ushortT* __restrict__ Bt,
             const float* __restrict__ bias, int M, int N, int K,
             ushortT* __restrict__ outb, float* __restrict__ outf,
             const float* __restrict__ resf, const ushortT* __restrict__ resb)
{
  __shared__ __align__(16) ushortT sm[65536];   // 128 KiB
  ushortT* const Ab0 = sm;
  ushortT* const Ab1 = sm + 16384;
  ushortT* const Bb0 = sm + 32768;
  ushortT* const Bb1 = sm + 49152;

  const int tid = threadIdx.x;
  const int w = tid >> 6, l = tid & 63;
  const int wr = w >> 2, wc = w & 3;

  // XCD-bijective swizzle
  const int nwg = gridDim.x * gridDim.y;
  int wg = blockIdx.y * gridDim.x + blockIdx.x;
  {
    const int q = nwg >> 3, r8 = nwg & 7;
    const int xc = wg & 7, yc = wg >> 3;
    wg = (xc < r8 ? xc * (q + 1) : r8 * (q + 1) + (xc - r8) * q) + yc;
  }
  const int nbn = N >> 8;
  const int mb = wg / nbn, nb = wg % nbn;
  const int m0 = mb << 8, n0 = nb << 8;
  const int NT = K >> 6;

  // staging source (per-lane, inverse-swizzled chunk) -- unchanged from R7
  const ushortT* gA = A  + (size_t)(m0 + w * 16 + (l >> 3)) * K + (((l & 7) ^ (l >> 3)) << 3);
  const ushortT* gB = Bt + (size_t)(n0 + w * 16 + (l >> 3)) * K + (((l & 7) ^ (l >> 3)) << 3);

  // ds_read byte addressing (same swizzle as R7, explicit for asm reads)
  const int rl = l & 15, ql = l >> 4;
  const int cchunk = (ql ^ (l & 7)) << 4;            // ks0 chunk byte
  unsigned adrA  = (unsigned)((wr * 128 + rl) * 128 + cchunk);          // A0 base
  unsigned adrB  = (unsigned)(65536 + (wc * 64 + rl) * 128 + cchunk);   // B0 base
  unsigned adrA1 = adrA ^ 64;                        // ks1 chunk = ks0 ^ 4 -> byte ^64
  unsigned adrB1 = adrB ^ 64;

  f32x4 acc[8][4];
  const f32x4 zero = {0.f, 0.f, 0.f, 0.f};
#pragma unroll
  for (int i = 0; i < 8; ++i)
#pragma unroll
    for (int j = 0; j < 4; ++j) acc[i][j] = zero;

  ushortT* Ac = Ab0; ushortT* An = Ab1;
  ushortT* Bc = Bb0; ushortT* Bn = Bb1;

  // prologue: stage tile 0, drain, publish, issue tile-0 ks0 reads
  STAGE_A2(Ac, 0, gA); STAGE_A2(Ac, 1, gA);
  STAGE_B2(Bc, 0, gB); STAGE_B2(Bc, 1, gB);
  VMC(0);
  BAR;

  short8 AfX[4], AfY[4], BfC[4];   // ks0 fragments
  short8 AfX2[4], AfY2[4], BfN[4]; // ks1 fragments
  size_t koff = 64;

  DSR_KS0();   // 12 reads in flight: AfX(4), BfC(4), AfY(4)

  for (int t = 0; t < NT; ++t) {
    if (t + 1 < NT) {
      STAGE_A2(An, 0, gA + koff); STAGE_A2(An, 1, gA + koff);
      STAGE_B2(Bn, 0, gB + koff); STAGE_B2(Bn, 1, gB + koff);
    }
    // Q0 (ks0, m0-3): need AfX+BfC -> leave AfY(4) outstanding
    LGKM(4);
    __builtin_amdgcn_s_setprio(1);
    QUAD(AfX, BfC, 0);
    __builtin_amdgcn_s_setprio(0);
    // issue ks1 m0-3 + B(ks1): outstanding = AfY(4)+AfX2(4)+BfN(4)=12
    DSR(AfX2[0], adrA1, 0);    DSR(AfX2[1], adrA1, 2048);
    DSR(AfX2[2], adrA1, 4096); DSR(AfX2[3], adrA1, 6144);
    DSR(BfN[0], adrB1, 0);     DSR(BfN[1], adrB1, 2048);
    DSR(BfN[2], adrB1, 4096);  DSR(BfN[3], adrB1, 6144);
    // Q1 (ks0, m4-7): need AfY -> leave 8
    LGKM(8);
    __builtin_amdgcn_s_setprio(1);
    QUAD(AfY, BfC, 4);
    __builtin_amdgcn_s_setprio(0);
    // issue ks1 m4-7: outstanding = AfX2(4)+BfN(4)+AfY2(4)=12
    DSR(AfY2[0], adrA1, 8192);  DSR(AfY2[1], adrA1, 10240);
    DSR(AfY2[2], adrA1, 12288); DSR(AfY2[3], adrA1, 14336);
    // Q2 (ks1, m0-3): need AfX2+BfN -> leave AfY2(4)
    LGKM(4);
    __builtin_amdgcn_s_setprio(1);
    QUAD(AfX2, BfN, 0);
    __builtin_amdgcn_s_setprio(0);
    // Q3 (ks1, m4-7)
    LGKM(0);
    __builtin_amdgcn_s_setprio(1);
    QUAD(AfY2, BfN, 4);
    __builtin_amdgcn_s_setprio(0);
    // boundary: t+1 staged loads were issued a full tile ago -> wait ~free
    if (t + 1 < NT) VMC(0);
    BAR;
    ushortT* tp;
    tp = Ac; Ac = An; An = tp;
    tp = Bc; Bc = Bn; Bn = tp;
    adrA ^= 0x8000; adrB ^= 0x8000; adrA1 ^= 0x8000; adrB1 ^= 0x8000;
    koff += 64;
    if (t + 1 < NT) DSR_KS0();   // next tile's 12 ks0 reads fly over the seam
  }

  // ---- epilogue: LDS round-trip -> fully coalesced stores ----
  float* const ep = (float*)sm;   // 32768 f32 = 128 KiB
#pragma unroll
  for (int p = 0; p < 2; ++p) {
    if (p) BAR;                   // protect overwrite from pass-0 readers
    if (wr == p) {
#pragma unroll
      for (int m = 0; m < 8; ++m) {
#pragma unroll
        for (int n = 0; n < 4; ++n) {
          const int c = wc * 64 + n * 16 + rl;
          const int pc = c ^ (c >> 3);
          *(f32x4*)(ep + (m * 4 + ql) * 1024 + pc * 4) = acc[m][n];
        }
      }
    }
    BAR;
#pragma unroll
    for (int k = 0; k < 4; ++k) {
      const int rb = w + k * 8;
      const int rowb = 16 * (rb >> 2) + 4 * (rb & 3);
      f32x4 rv[4];
#pragma unroll
      for (int j = 0; j < 4; ++j) {
        const int c = 4 * l + j;
        const int pc = c ^ (c >> 3);
        rv[j] = *(const f32x4*)(ep + rb * 1024 + pc * 4);
      }
      const int col = n0 + 4 * l;
      const float4v bb = *(const float4v*)(bias + col);
#pragma unroll
      for (int i = 0; i < 4; ++i) {
        const size_t row = (size_t)(m0 + p * 128 + rowb + i);
        float v0 = rv[0][i] + bb[0], v1 = rv[1][i] + bb[1],
              v2 = rv[2][i] + bb[2], v3 = rv[3][i] + bb[3];
        if constexpr (EPI == 1) {
          const float4v rr = *(const float4v*)(resf + row * (size_t)N + col);
          v0 += rr[0]; v1 += rr[1]; v2 += rr[2]; v3 += rr[3];
        }
        if constexpr (EPI == 2) {
          v0 = fast_gelu(v0); v1 = fast_gelu(v1); v2 = fast_gelu(v2); v3 = fast_gelu(v3);
        }
        if constexpr (EPI == 3) {
          const short4v rb4 = *(const short4v*)(resb + row * (size_t)N + col);
          v0 += bf2f((ushortT)rb4[0]); v1 += bf2f((ushortT)rb4[1]);
          v2 += bf2f((ushortT)rb4[2]); v3 += bf2f((ushortT)rb4[3]);
          float4v o = {v0, v1, v2, v3};
          *(float4v*)(outf + row * (size_t)N + col) = o;
        } else {
          short4v o;
          o[0] = (short)f2bf(v0); o[1] = (short)f2bf(v1);
          o[2] = (short)f2bf(v2); o[3] = (short)f2bf(v3);
          *(short4v*)(outb + row * (size_t)N + col) = o;
        }
      }
    }
  }
}

// ---------------- windowed attention (one block/window, one wave/head) ----------------
__global__ __launch_bounds__(512)
void attn_kernel(const ushortT* __restrict__ qkv, ushortT* __restrict__ out)
{
  __shared__ __align__(16) ushortT sq[8][1544];
  const int wb = blockIdx.x;
  const int b  = wb >> 9;
  const int rr = wb & 511;
  const int w1 = rr >> 6;
  const int g  = rr & 63;
  const int tid = threadIdx.x;

#pragma unroll
  for (int c = 0; c < 3; ++c) {
    const int f = c * 512 + tid;
    const int i = f / 192;
    const int col = (f % 192) * 8;
    const int tin = (64 * g + 8 * i + w1 + 4) & (NSEQ - 1);
    const ushortT* src = qkv + ((size_t)b * NSEQ + tin) * 1536 + col;
    *(short8*)(&sq[i][col]) = *(const short8*)src;
  }
  __syncthreads();

  const int wave = tid >> 6, lane = tid & 63;
  const int h = wave;
  const int qi = lane >> 3, kj = lane & 7;

  float s = 0.f;
  const ushortT* qrow = &sq[qi][h * 64];
  const ushortT* krow = &sq[kj][512 + h * 64];
#pragma unroll
  for (int c = 0; c < 8; ++c) {
    short8 qa = *(const short8*)(qrow + c * 8);
    short8 ka = *(const short8*)(krow + c * 8);
#pragma unroll
    for (int j = 0; j < 8; ++j) s += bf2f((ushortT)qa[j]) * bf2f((ushortT)ka[j]);
  }
  s *= 0.125f;

  const int pq = 64 * g + 8 * qi + w1;
  const int pk = 64 * g + 8 * kj + w1;
  const int cq = (pq < 4088) ? 0 : (pq < 4092 ? 1 : 2);
  const int ck = (pk < 4088) ? 0 : (pk < 4092 ? 1 : 2);
  if (cq != ck) s -= 100.f;

  float mx = s;
  mx = fmaxf(mx, __shfl_xor(mx, 1, 64));
  mx = fmaxf(mx, __shfl_xor(mx, 2, 64));
  mx = fmaxf(mx, __shfl_xor(mx, 4, 64));
  const float e = expf(s - mx);
  float sum = e;
  sum += __shfl_xor(sum, 1, 64);
  sum += __shfl_xor(sum, 2, 64);
  sum += __shfl_xor(sum, 4, 64);
  const float p = e / sum;

  const int dc = lane & 7;
  float o[8];
#pragma unroll
  for (int j = 0; j < 8; ++j) o[j] = 0.f;
#pragma unroll
  for (int k2 = 0; k2 < 8; ++k2) {
    const float pk2 = __shfl(p, (lane & ~7) + k2, 64);
    short8 va = *(const short8*)(&sq[k2][1024 + h * 64 + dc * 8]);
#pragma unroll
    for (int j = 0; j < 8; ++j) o[j] += pk2 * bf2f((ushortT)va[j]);
  }

  const int tout = (512 * qi + 64 * w1 + g + 4) & (NSEQ - 1);
  short8 ov;
#pragma unroll
  for (int j = 0; j < 8; ++j) ov[j] = (short)f2bf(o[j]);
  *(short8*)(out + ((size_t)b * NSEQ + tout) * DIM + h * 64 + dc * 8) = ov;
}

// ---------------- host ----------------
extern "C" void kernel_launch(void* const* d_in, const int* in_sizes, int n_in,
                              void* d_out, int out_size, void* d_ws, size_t ws_size,
                              hipStream_t stream) {
  const float* x      = (const float*)d_in[0];
  const float* n1g    = (const float*)d_in[1];
  const float* n1b    = (const float*)d_in[2];
  const float* qkv_w  = (const float*)d_in[3];
  const float* qkv_b  = (const float*)d_in[4];
  const float* proj_w = (const float*)d_in[5];
  const float* proj_b = (const float*)d_in[6];
  const float* n2g    = (const float*)d_in[7];
  const float* n2b    = (const float*)d_in[8];
  const float* fc1_w  = (const float*)d_in[9];
  const float* fc1_b  = (const float*)d_in[10];
  const float* fc2_w  = (const float*)d_in[11];
  const float* fc2_b  = (const float*)d_in[12];
  float* out = (float*)d_out;

  size_t off = 0;
  char* ws = (char*)d_ws;
  auto alloc = [&](size_t b) { void* p = ws + off; off += (b + 255) & ~(size_t)255; return p; };

  ushortT* qkvw_b = (ushortT*)alloc((size_t)1536 * 512 * 2);
  ushortT* projw_b = (ushortT*)alloc((size_t)512 * 512 * 2);
  ushortT* fc1w_b = (ushortT*)alloc((size_t)2048 * 512 * 2);
  ushortT* fc2w_b = (ushortT*)alloc((size_t)512 * 2048 * 2);
  ushortT* bufA = (ushortT*)alloc((size_t)TOK * 512 * 2);    // xn -> attnout -> h_in
  ushortT* bufQ = (ushortT*)alloc((size_t)TOK * 1536 * 2);   // qkv ; then x1 (bf16)
  ushortT* x1 = bufQ;

  int nch = 1;
  while (nch < 16) {
    size_t need = (size_t)(TOK / nch) * 2048 * 2;
    if (off + need <= ws_size) break;
    nch <<= 1;
  }
  ushortT* h1 = (ushortT*)(ws + off);

  cvt_kernel<<<(1536 * 512 / 4 + 255) / 256, 256, 0, stream>>>(qkv_w, qkvw_b, 1536 * 512 / 4);
  cvt_kernel<<<(512 * 512 / 4 + 255) / 256, 256, 0, stream>>>(proj_w, projw_b, 512 * 512 / 4);
  cvt_kernel<<<(2048 * 512 / 4 + 255) / 256, 256, 0, stream>>>(fc1_w, fc1w_b, 2048 * 512 / 4);
  cvt_kernel<<<(512 * 2048 / 4 + 255) / 256, 256, 0, stream>>>(fc2_w, fc2w_b, 512 * 2048 / 4);

  ln_kernel<false><<<TOK / 4, 256, 0, stream>>>(x, n1g, n1b, bufA);

  gemm256<0><<<dim3(TOK / 256, 1536 / 256), 512, 0, stream>>>(
      bufA, qkvw_b, qkv_b, TOK, 1536, 512, bufQ, nullptr, nullptr, nullptr);

  attn_kernel<<<8192, 512, 0, stream>>>(bufQ, bufA);

  gemm256<1><<<dim3(TOK / 256, 512 / 256), 512, 0, stream>>>(
      bufA, projw_b, proj_b, TOK, 512, 512, x1, nullptr, x, nullptr);

  ln_kernel<true><<<TOK / 4, 256, 0, stream>>>(x1, n2g, n2b, bufA);

  const int tc = TOK / nch;
  for (int c = 0; c < nch; ++c) {
    const ushortT* hin = bufA + (size_t)c * tc * 512;
    gemm256<2><<<dim3(tc / 256, 2048 / 256), 512, 0, stream>>>(
        hin, fc1w_b, fc1_b, tc, 2048, 512, h1, nullptr, nullptr, nullptr);
    gemm256<3><<<dim3(tc / 256, 512 / 256), 512, 0, stream>>>(
        h1, fc2w_b, fc2_b, tc, 512, 2048, nullptr, out + (size_t)c * tc * 512,
        nullptr, x1 + (size_t)c * tc * 512);
  }
}